// Round 2
// baseline (9763.142 us; speedup 1.0000x reference)
//
// LSTMDecoder on MI355X — round 2: same pipeline, bf16 -> fp16 everywhere.
//
// Journal:
// * R1 failed absmax 0.0898 vs 0.0198: bf16 (8-bit mantissa) rounding amplified ~20x by the
//   attention logit dot (sqrt(K)*sigma(enc_proj) ~ 32*0.64), recirculated 48 steps. Error budget
//   matched measurement => precision problem, not a structural bug.
// * Fix: fp16 storage + v_mfma_f32_16x16x32_f16 (same rate as bf16, 8x lower rounding).
//   All values O(1) => no fp16 overflow risk. Plus fp32 h2 copy for the e_t dot (free).
// * Structure unchanged: 4 kernels/step; split-K fp32 partial slices (no atomics, no zero-init,
//   rewritten every call => safe under 0xAA re-poison); c1/c2 fp32; pre1 fp32.

#include <hip/hip_runtime.h>

static constexpr int Bn = 64, Ln = 128, Tn = 48, En = 512, HEn = 1024, Hn = 1024, Gn = 4096;

typedef _Float16 h16;
typedef __attribute__((ext_vector_type(8))) _Float16 h16x8;
typedef __attribute__((ext_vector_type(2))) _Float16 h16x2;
typedef __attribute__((ext_vector_type(4))) float f32x4;

__device__ __forceinline__ float sigf(float x){ return 1.f / (1.f + expf(-x)); }

// ---------------- fp32 -> fp16 conversion (2 elems/thread) ----------------
__global__ void cvt2(const float* __restrict__ in, h16x2* __restrict__ out, int n2){
  int i = blockIdx.x * blockDim.x + threadIdx.x;
  int stride = gridDim.x * blockDim.x;
  for (; i < n2; i += stride){
    float2 v = reinterpret_cast<const float2*>(in)[i];
    h16x2 o; o.x = (h16)v.x; o.y = (h16)v.y;
    out[i] = o;
  }
}

// ---------------- state init ----------------
__global__ void init_state(const float* __restrict__ h1i, const float* __restrict__ c1i,
                           const float* __restrict__ h2i, const float* __restrict__ c2i,
                           h16* __restrict__ h1h, float* __restrict__ c1,
                           h16* __restrict__ h2h, float* __restrict__ c2,
                           float* __restrict__ h2f, h16* __restrict__ oh){
  int i = blockIdx.x * blockDim.x + threadIdx.x;
  if (i < Bn * Hn){
    h1h[i] = (h16)h1i[i]; c1[i] = c1i[i];
    h2h[i] = (h16)h2i[i]; c2[i] = c2i[i];
    h2f[i] = h2i[i];
    oh[i] = (h16)0.f;
  }
}

// ---------------- generic MFMA GEMM strip ----------------
// out[m][n] = sum_k A[m][k]*Bw[n][k] + bias0[n] + bias1[n]
// block tile: 64 rows (bx) x 256 cols (by); wave w owns rows bx*64+w*16, all 16 n-tiles.
__device__ void gemm_strip(int bx, int by, int tid,
                           const h16* __restrict__ A, int lda,
                           const h16* __restrict__ Bw, int ldb,
                           const float* __restrict__ bias0, const float* __restrict__ bias1,
                           float* __restrict__ outF, h16* __restrict__ outH,
                           int ldc, int K)
{
  int w = tid >> 6, lane = tid & 63;
  int la = lane & 15, q = lane >> 4;
  int m0 = bx * 64 + w * 16;
  int n0 = by * 256;
  f32x4 acc[16];
  #pragma unroll
  for (int i = 0; i < 16; i++) acc[i] = (f32x4){0.f, 0.f, 0.f, 0.f};
  const h16* arow = A + (size_t)(m0 + la) * lda + q * 8;
  for (int k0 = 0; k0 < K; k0 += 32){
    h16x8 af = *reinterpret_cast<const h16x8*>(arow + k0);
    #pragma unroll
    for (int nt = 0; nt < 16; nt++){
      const h16* brow = Bw + (size_t)(n0 + nt * 16 + la) * ldb + k0 + q * 8;
      h16x8 bf = *reinterpret_cast<const h16x8*>(brow);
      acc[nt] = __builtin_amdgcn_mfma_f32_16x16x32_f16(af, bf, acc[nt], 0, 0, 0);
    }
  }
  int mrow = m0 + q * 4;
  #pragma unroll
  for (int nt = 0; nt < 16; nt++){
    int n = n0 + nt * 16 + la;
    float bs = (bias0 ? bias0[n] : 0.f) + (bias1 ? bias1[n] : 0.f);
    #pragma unroll
    for (int r = 0; r < 4; r++){
      float v = acc[nt][r] + bs;
      size_t off = (size_t)(mrow + r) * ldc + n;
      if (outF) outF[off] = v;
      else      outH[off] = (h16)v;
    }
  }
}

__global__ void gemm_kernel(const h16* __restrict__ A, int lda,
                            const h16* __restrict__ Bw, int ldb,
                            const float* __restrict__ bias0, const float* __restrict__ bias1,
                            float* __restrict__ outF, h16* __restrict__ outH,
                            int ldc, int K){
  gemm_strip(blockIdx.x, blockIdx.y, threadIdx.x, A, lda, Bw, ldb, bias0, bias1, outF, outH, ldc, K);
}

// ---------------- gates partial GEMM (split-K) ----------------
// block = (gi4 in [0,64), chunk c). Covers gate-cols [gi4*64, +64), all 64 b-rows,
// k in [0,512) relative to caller-offset A/Bw. Wave w takes k-sub [w*128,+128).
// Stores fp32 tiles to gp[slice = c*4 + w][64][4096]. Plain stores, no init needed.
__device__ void ggemm(int gi4, int c, int tid,
                      const h16* __restrict__ A,
                      const h16* __restrict__ Bw, int ldb,
                      float* __restrict__ gp)
{
  int w = tid >> 6, lane = tid & 63;
  int la = lane & 15, q = lane >> 4;
  f32x4 acc[4][4];
  #pragma unroll
  for (int mi = 0; mi < 4; mi++)
    #pragma unroll
    for (int nt = 0; nt < 4; nt++) acc[mi][nt] = (f32x4){0.f, 0.f, 0.f, 0.f};
  for (int kk = 0; kk < 128; kk += 32){
    int k = w * 128 + kk + q * 8;
    h16x8 af[4], bfr[4];
    #pragma unroll
    for (int mi = 0; mi < 4; mi++)
      af[mi] = *reinterpret_cast<const h16x8*>(A + (size_t)(mi * 16 + la) * Hn + k);
    #pragma unroll
    for (int nt = 0; nt < 4; nt++)
      bfr[nt] = *reinterpret_cast<const h16x8*>(Bw + (size_t)(gi4 * 64 + nt * 16 + la) * ldb + k);
    #pragma unroll
    for (int mi = 0; mi < 4; mi++)
      #pragma unroll
      for (int nt = 0; nt < 4; nt++)
        acc[mi][nt] = __builtin_amdgcn_mfma_f32_16x16x32_f16(af[mi], bfr[nt], acc[mi][nt], 0, 0, 0);
  }
  float* dst = gp + (size_t)(c * 4 + w) * Bn * Gn;
  #pragma unroll
  for (int mi = 0; mi < 4; mi++)
    #pragma unroll
    for (int nt = 0; nt < 4; nt++)
      #pragma unroll
      for (int r = 0; r < 4; r++)
        dst[(size_t)(mi * 16 + q * 4 + r) * Gn + gi4 * 64 + nt * 16 + la] = acc[mi][nt][r];
}

// ---------------- K1: gates2 GEMM (flat K = 3072 over [h1 | o_prev | h2]) ----------------
__global__ void k1_g2gemm(const h16* __restrict__ h1h,
                          const h16* __restrict__ oh,
                          const h16* __restrict__ h2h,
                          const h16* __restrict__ wih2,
                          const h16* __restrict__ whh2,
                          float* __restrict__ gp2){
  int bid = blockIdx.x;
  int gi4 = bid & 63;
  int c = bid >> 6;            // 0..5, 512-wide flat-k chunks
  const h16 *A, *Bw; int ldb;
  if (c < 2){       A = h1h + c * 512;        Bw = wih2 + c * 512; ldb = 2 * Hn; }
  else if (c < 4){  A = oh  + (c - 2) * 512;  Bw = wih2 + c * 512; ldb = 2 * Hn; }
  else {            A = h2h + (c - 4) * 512;  Bw = whh2 + (c - 4) * 512; ldb = Hn; }
  ggemm(gi4, c, threadIdx.x, A, Bw, ldb, gp2);
}

// ---------------- K2: g2 epilogue -> h2,c2  |  g1 GEMM for step t+1 ----------------
__global__ void k2_epi_g1(const float* __restrict__ gp2,
                          const float* __restrict__ bih2, const float* __restrict__ bhh2,
                          float* __restrict__ c2, h16* __restrict__ h2h,
                          float* __restrict__ h2f,
                          const h16* __restrict__ h1h,
                          const h16* __restrict__ whh1,
                          float* __restrict__ gp1,
                          int epi_blocks){
  int bid = blockIdx.x;
  if (bid < epi_blocks){
    int b = bid;
    for (int qq = 0; qq < 4; qq++){
      int j = threadIdx.x + qq * 256;
      float gi = 0.f, gf = 0.f, gg = 0.f, go = 0.f;
      for (int s = 0; s < 24; s++){
        const float* base = gp2 + (size_t)s * Bn * Gn + (size_t)b * Gn;
        gi += base[j]; gf += base[j + 1024]; gg += base[j + 2048]; go += base[j + 3072];
      }
      gi += bih2[j] + bhh2[j];
      gf += bih2[j + 1024] + bhh2[j + 1024];
      gg += bih2[j + 2048] + bhh2[j + 2048];
      go += bih2[j + 3072] + bhh2[j + 3072];
      float i_ = sigf(gi), f_ = sigf(gf), g_ = tanhf(gg), o_ = sigf(go);
      float c_ = f_ * c2[b * Hn + j] + i_ * g_;
      c2[b * Hn + j] = c_;
      float h_ = o_ * tanhf(c_);
      h2h[b * Hn + j] = (h16)h_;
      h2f[b * Hn + j] = h_;
    }
  } else {
    int gb = bid - epi_blocks;
    int gi4 = gb & 63;
    int c = gb >> 6;           // 0..1
    ggemm(gi4, c, threadIdx.x, h1h + c * 512, whh1 + c * 512, Hn, gp1);
  }
}

// ---------------- K3: e_t dots | hw GEMM | g1 epilogue -> h1,c1 ----------------
__global__ void k3_e_hw_epi(int t_next, int e_cnt, int hw_cnt,
                            const float* __restrict__ gp1, const float* __restrict__ pre1,
                            float* __restrict__ c1, h16* __restrict__ h1h,
                            const h16* __restrict__ h2h, const float* __restrict__ h2f,
                            const h16* __restrict__ eph,
                            const int* __restrict__ msk, float* __restrict__ ebuf,
                            const h16* __restrict__ wcombh, const float* __restrict__ bcomb,
                            float* __restrict__ hwb){
  int bid = blockIdx.x;
  if (bid < e_cnt){
    // e_t[b,l] = h2[b] . enc_proj[b,l]; 4 waves/block, 4 l's per wave. h2 in fp32.
    int w = threadIdx.x >> 6, lane = threadIdx.x & 63;
    int wv = bid * 4 + w;           // 0..2047
    int b = wv >> 5;
    int lg = (wv & 31) * 4;
    const float* h2r = h2f + b * Hn + lane * 16;
    float hv[16];
    #pragma unroll
    for (int i = 0; i < 16; i++) hv[i] = h2r[i];
    for (int li = 0; li < 4; li++){
      int l = lg + li;
      const h16* er = eph + ((size_t)b * Ln + l) * Hn + lane * 16;
      float acc = 0.f;
      #pragma unroll
      for (int i = 0; i < 16; i++) acc += hv[i] * (float)er[i];
      for (int off = 32; off; off >>= 1) acc += __shfl_xor(acc, off);
      if (lane == 0) ebuf[b * Ln + l] = msk[b * Ln + l] ? -1e30f : acc;
    }
  } else if (bid < e_cnt + hw_cnt){
    int gb = bid - e_cnt;           // 0..3 -> n strips of 256
    gemm_strip(0, gb, threadIdx.x, h2h, Hn, wcombh + HEn, HEn + Hn,
               bcomb, nullptr, hwb, nullptr, Hn, Hn);
  } else {
    int b = bid - e_cnt - hw_cnt;   // 0..63 (present only when t_next < Tn)
    for (int qq = 0; qq < 4; qq++){
      int j = threadIdx.x + qq * 256;
      float gi = 0.f, gf = 0.f, gg = 0.f, go = 0.f;
      for (int s = 0; s < 8; s++){
        const float* base = gp1 + (size_t)s * Bn * Gn + (size_t)b * Gn;
        gi += base[j]; gf += base[j + 1024]; gg += base[j + 2048]; go += base[j + 3072];
      }
      const float* p = pre1 + ((size_t)t_next * Bn + b) * Gn;
      gi += p[j]; gf += p[j + 1024]; gg += p[j + 2048]; go += p[j + 3072];
      float i_ = sigf(gi), f_ = sigf(gf), g_ = tanhf(gg), o_ = sigf(go);
      float c_ = f_ * c1[b * Hn + j] + i_ * g_;
      c1[b * Hn + j] = c_;
      h1h[b * Hn + j] = (h16)(o_ * tanhf(c_));
    }
  }
}

// ---------------- K4: softmax over e + o_t = tanh(sum_l alpha*enc_comb + hw) ----------------
__global__ void k4_out(int t, const float* __restrict__ ebuf,
                       const h16* __restrict__ ecbh, const float* __restrict__ hwb,
                       float* __restrict__ out, h16* __restrict__ oh){
  __shared__ float sa[Ln], sb[Ln];
  int bid = blockIdx.x;
  int b = bid >> 1;
  int jh = (bid & 1) * 512;
  int tid = threadIdx.x;
  if (tid < Ln) sa[tid] = ebuf[b * Ln + tid];
  __syncthreads();
  float m = -1e30f;
  for (int l = 0; l < Ln; l++) m = fmaxf(m, sa[l]);
  if (tid < Ln) sb[tid] = expf(sa[tid] - m);
  __syncthreads();
  float s = 0.f;
  for (int l = 0; l < Ln; l++) s += sb[l];
  float rinv = 1.f / s;
  int j0 = jh + tid * 2;
  const h16* base = ecbh + (size_t)b * Ln * Hn + j0;
  float a0 = 0.f, a1 = 0.f;
  for (int l = 0; l < Ln; l++){
    float al = sb[l];
    h16x2 pq = *reinterpret_cast<const h16x2*>(base + (size_t)l * Hn);
    a0 += al * (float)pq.x;
    a1 += al * (float)pq.y;
  }
  a0 *= rinv; a1 *= rinv;
  float2 hw2 = *reinterpret_cast<const float2*>(hwb + b * Hn + j0);
  float o0 = tanhf(a0 + hw2.x);
  float o1 = tanhf(a1 + hw2.y);
  *reinterpret_cast<float2*>(out + ((size_t)t * Bn + b) * Hn + j0) = make_float2(o0, o1);
  h16x2 opk; opk.x = (h16)o0; opk.y = (h16)o1;
  *reinterpret_cast<h16x2*>(oh + b * Hn + j0) = opk;
}

// ---------------- host ----------------
extern "C" void kernel_launch(void* const* d_in, const int* in_sizes, int n_in,
                              void* d_out, int out_size, void* d_ws, size_t ws_size,
                              hipStream_t stream)
{
  const float* enc   = (const float*)d_in[0];
  const int*   msk   = (const int*)  d_in[1];
  const float* h1i   = (const float*)d_in[2];
  const float* c1i   = (const float*)d_in[3];
  const float* h2i   = (const float*)d_in[4];
  const float* c2i   = (const float*)d_in[5];
  const float* caps  = (const float*)d_in[6];
  const float* Wih1  = (const float*)d_in[7];
  const float* Whh1  = (const float*)d_in[8];
  const float* bih1  = (const float*)d_in[9];
  const float* bhh1  = (const float*)d_in[10];
  const float* Wih2  = (const float*)d_in[11];
  const float* Whh2  = (const float*)d_in[12];
  const float* bih2  = (const float*)d_in[13];
  const float* bhh2  = (const float*)d_in[14];
  const float* Watt  = (const float*)d_in[15];
  const float* batt  = (const float*)d_in[16];
  const float* Wcomb = (const float*)d_in[17];
  const float* bcomb = (const float*)d_in[18];
  float* out = (float*)d_out;

  char* p = (char*)d_ws;
  auto take = [&](size_t bytes){ char* r = p; p += (bytes + 255) & ~(size_t)255; return r; };
  float* pre1   = (float*)take((size_t)Tn * Bn * Gn * 4);          // 50.3 MB
  float* gp2    = (float*)take((size_t)24 * Bn * Gn * 4);          // 25.2 MB
  float* gp1    = (float*)take((size_t)8 * Bn * Gn * 4);           //  8.4 MB
  h16*   ench   = (h16*)take((size_t)Bn * Ln * HEn * 2);
  h16*   eph    = (h16*)take((size_t)Bn * Ln * Hn * 2);
  h16*   ecbh   = (h16*)take((size_t)Bn * Ln * Hn * 2);
  h16*   caph   = (h16*)take((size_t)Tn * Bn * En * 2);
  h16*   wih1h  = (h16*)take((size_t)Gn * En * 2);
  h16*   whh1h  = (h16*)take((size_t)Gn * Hn * 2);
  h16*   wih2h  = (h16*)take((size_t)Gn * 2 * Hn * 2);
  h16*   whh2h  = (h16*)take((size_t)Gn * Hn * 2);
  h16*   watth  = (h16*)take((size_t)Hn * HEn * 2);
  h16*   wcombh = (h16*)take((size_t)Hn * (HEn + Hn) * 2);
  h16*   h1h    = (h16*)take((size_t)Bn * Hn * 2);
  h16*   h2h    = (h16*)take((size_t)Bn * Hn * 2);
  h16*   oh     = (h16*)take((size_t)Bn * Hn * 2);
  float* c1     = (float*)take((size_t)Bn * Hn * 4);
  float* c2     = (float*)take((size_t)Bn * Hn * 4);
  float* h2f    = (float*)take((size_t)Bn * Hn * 4);
  float* ebuf   = (float*)take((size_t)Bn * Ln * 4);
  float* hwb    = (float*)take((size_t)Bn * Hn * 4);
  (void)ws_size; (void)n_in; (void)in_sizes; (void)out_size;

  auto cvt = [&](const float* src, void* dst, int n){
    int n2 = n / 2;
    int blocks = (n2 + 255) / 256; if (blocks > 2048) blocks = 2048;
    cvt2<<<blocks, 256, 0, stream>>>(src, (h16x2*)dst, n2);
  };
  cvt(enc,   ench,   Bn * Ln * HEn);
  cvt(caps,  caph,   Tn * Bn * En);
  cvt(Wih1,  wih1h,  Gn * En);
  cvt(Whh1,  whh1h,  Gn * Hn);
  cvt(Wih2,  wih2h,  Gn * 2 * Hn);
  cvt(Whh2,  whh2h,  Gn * Hn);
  cvt(Watt,  watth,  Hn * HEn);
  cvt(Wcomb, wcombh, Hn * (HEn + Hn));

  init_state<<<(Bn * Hn) / 256, 256, 0, stream>>>(h1i, c1i, h2i, c2i, h1h, c1, h2h, c2, h2f, oh);

  // pre1 = captions @ Wih1^T + bih1 + bhh1   (3072 x 4096, K=512)
  gemm_kernel<<<dim3((Tn * Bn) / 64, Gn / 256), 256, 0, stream>>>(
      caph, En, wih1h, En, bih1, bhh1, pre1, nullptr, Gn, En);
  // enc_proj = enc @ Watt^T + batt  (8192 x 1024, K=1024) -> fp16
  gemm_kernel<<<dim3((Bn * Ln) / 64, Hn / 256), 256, 0, stream>>>(
      ench, HEn, watth, HEn, batt, nullptr, nullptr, eph, Hn, HEn);
  // enc_comb = enc @ Wcomb[:, :HE]^T  (8192 x 1024, K=1024) -> fp16
  gemm_kernel<<<dim3((Bn * Ln) / 64, Hn / 256), 256, 0, stream>>>(
      ench, HEn, wcombh, HEn + Hn, nullptr, nullptr, nullptr, ecbh, Hn, HEn);

  // warm-up: g1 GEMM + epilogue for t=0 (h1[-1] = init)
  k2_epi_g1<<<128, 256, 0, stream>>>(gp2, bih2, bhh2, c2, h2h, h2f, h1h, whh1h, gp1, /*epi_blocks=*/0);
  k3_e_hw_epi<<<64, 256, 0, stream>>>(0, /*e_cnt=*/0, /*hw_cnt=*/0,
      gp1, pre1, c1, h1h, h2h, h2f, eph, msk, ebuf, wcombh, bcomb, hwb);

  for (int t = 0; t < Tn; t++){
    k1_g2gemm<<<384, 256, 0, stream>>>(h1h, oh, h2h, wih2h, whh2h, gp2);
    int g1on = (t < Tn - 1) ? 1 : 0;
    k2_epi_g1<<<64 + g1on * 128, 256, 0, stream>>>(gp2, bih2, bhh2, c2, h2h, h2f, h1h, whh1h, gp1, 64);
    k3_e_hw_epi<<<512 + 4 + g1on * 64, 256, 0, stream>>>(t + 1, 512, 4,
        gp1, pre1, c1, h1h, h2h, h2f, eph, msk, ebuf, wcombh, bcomb, hwb);
    k4_out<<<128, 256, 0, stream>>>(t, ebuf, ecbh, hwb, out, oh);
  }
}

// Round 7
// 6655.237 us; speedup vs baseline: 1.4670x; 1.4670x over previous
//
// LSTMDecoder on MI355X — round 7: R6 resubmit with kA de-risked to 256-thread blocks.
//
// Journal:
// * R2: multi-kernel PASSED 0.0117 @ 9763us (155us gemm_kernel = per-MFMA vmcnt serialization,
//   VGPR=64; ~190us/step loop). All R2 kernels were 256-thread.
// * R3: cooperative launch fails silently under graph capture. R4/R5: spin-barrier designs ->
//   container killed (deadlock; zero/low-slack residency). BARRIER ABANDONED.
// * R6: barrier-free multi-kernel (gemm8 batched loads, fused kA 512-thr, kB, kC) -> container
//   failed twice AGAIN despite full re-audit finding no fault. Hypothesis: node poisoned by R4's
//   deadlock (R5/R6 victims), or infra flake. R6 is structurally the R2 pattern that ran fine.
// * R7: resubmit R6 with kA reshaped to the proven 256-thread/4-wave config: wave g accumulates
//   gate g over FULL flat-K (no k-half split), LDS sg[4][64][17] (17KB), epilogue in-kernel.
//   gemm8/kB/kC unchanged. 3 kernels/step, no split-K partial traffic, h1/h2 double-buffered.
// * Numerics: fp16 MFMA fp32-acc, c-state fp32, fp32 h2 copy for e-dot (proven 0.0117 schedule).

#include <hip/hip_runtime.h>

static constexpr int Bn = 64, Ln = 128, Tn = 48, En = 512, HEn = 1024, Hn = 1024, Gn = 4096;

typedef _Float16 h16;
typedef __attribute__((ext_vector_type(8))) _Float16 h16x8;
typedef __attribute__((ext_vector_type(2))) _Float16 h16x2;
typedef __attribute__((ext_vector_type(4))) float f32x4;

__device__ __forceinline__ float sigf(float x){ return 1.f / (1.f + expf(-x)); }

// ---------------- fp32 -> fp16 conversion ----------------
__global__ void cvt2(const float* __restrict__ in, h16x2* __restrict__ out, int n2){
  int i = blockIdx.x * blockDim.x + threadIdx.x;
  int stride = gridDim.x * blockDim.x;
  for (; i < n2; i += stride){
    float2 v = reinterpret_cast<const float2*>(in)[i];
    h16x2 o; o.x = (h16)v.x; o.y = (h16)v.y;
    out[i] = o;
  }
}

// ---------------- state init ----------------
__global__ void init_state(const float* __restrict__ h1i, const float* __restrict__ c1i,
                           const float* __restrict__ h2i, const float* __restrict__ c2i,
                           h16* __restrict__ h1a, float* __restrict__ c1,
                           h16* __restrict__ h2a, float* __restrict__ c2,
                           float* __restrict__ h2f, h16* __restrict__ oh){
  int i = blockIdx.x * blockDim.x + threadIdx.x;
  if (i < Bn * Hn){
    h1a[i] = (h16)h1i[i]; c1[i] = c1i[i];
    h2a[i] = (h16)h2i[i]; c2[i] = c2i[i];
    h2f[i] = h2i[i];
    oh[i] = (h16)0.f;
  }
}

// ---------------- setup GEMM: 64 rows x 128 cols / block, batched loads ----------------
__global__ __launch_bounds__(256, 4) void gemm8(
    const h16* __restrict__ A, int lda,
    const h16* __restrict__ Bw, int ldb,
    const float* __restrict__ bias0, const float* __restrict__ bias1,
    float* __restrict__ outF, h16* __restrict__ outH, int ldc, int K)
{
  int w = threadIdx.x >> 6, lane = threadIdx.x & 63;
  int la = lane & 15, q = lane >> 4;
  int m0 = blockIdx.x * 64 + w * 16;
  int n0 = blockIdx.y * 128;
  f32x4 acc[8];
  #pragma unroll
  for (int i = 0; i < 8; i++) acc[i] = (f32x4){0.f, 0.f, 0.f, 0.f};
  const h16* arow = A + (size_t)(m0 + la) * lda + q * 8;
  for (int k0 = 0; k0 < K; k0 += 32){
    h16x8 af = *reinterpret_cast<const h16x8*>(arow + k0);
    h16x8 bf[8];
    #pragma unroll
    for (int nt = 0; nt < 8; nt++)
      bf[nt] = *reinterpret_cast<const h16x8*>(Bw + (size_t)(n0 + nt * 16 + la) * ldb + k0 + q * 8);
    #pragma unroll
    for (int nt = 0; nt < 8; nt++)
      acc[nt] = __builtin_amdgcn_mfma_f32_16x16x32_f16(af, bf[nt], acc[nt], 0, 0, 0);
  }
  int mrow = m0 + q * 4;
  #pragma unroll
  for (int nt = 0; nt < 8; nt++){
    int n = n0 + nt * 16 + la;
    float bs = (bias0 ? bias0[n] : 0.f) + (bias1 ? bias1[n] : 0.f);
    #pragma unroll
    for (int r = 0; r < 4; r++){
      float v = acc[nt][r] + bs;
      size_t off = (size_t)(mrow + r) * ldc + n;
      if (outF) outF[off] = v;
      else      outH[off] = (h16)v;
    }
  }
}

// ---------------- segment GEMM helper (4 m-tiles x 16 cols, batched loads) ----------------
__device__ __forceinline__ void gseg(int nsteps,
                                     const h16* __restrict__ Ap, int astart,
                                     const h16* __restrict__ Bp, int bstr, int bstart,
                                     int la, int q, int n0, f32x4* acc){
  for (int s = 0; s < nsteps; s++){
    int ka = astart + s * 32 + q * 8;
    int kb = bstart + s * 32 + q * 8;
    h16x8 af[4], bf;
    #pragma unroll
    for (int mi = 0; mi < 4; mi++)
      af[mi] = *reinterpret_cast<const h16x8*>(Ap + (size_t)(mi * 16 + la) * Hn + ka);
    bf = *reinterpret_cast<const h16x8*>(Bp + (size_t)(n0 + la) * bstr + kb);
    #pragma unroll
    for (int mi = 0; mi < 4; mi++)
      acc[mi] = __builtin_amdgcn_mfma_f32_16x16x32_f16(af[mi], bf, acc[mi], 0, 0, 0);
  }
}

// ---------------- kA: fused gates2(t) [blocks 0-63] + gates1(t+1) [blocks 64-127] ----------
// 256 threads, 4 waves; wave g accumulates gate g over the FULL flat K.
// mode 0 (prime, 64 blocks): all blocks do gates1 with pre1_t (t=0).
// mode 1 (normal, 128 blocks): bid<64 gates2; bid>=64 gates1 (skipped when pre1_t==nullptr).
__global__ __launch_bounds__(256, 2) void kA(
    const h16* __restrict__ h1cur, const h16* __restrict__ h2prev, const h16* __restrict__ oh,
    h16* __restrict__ h1next, h16* __restrict__ h2cur, float* __restrict__ h2f,
    float* __restrict__ c1, float* __restrict__ c2,
    const h16* __restrict__ wih2, const h16* __restrict__ whh2, const h16* __restrict__ whh1,
    const float* __restrict__ bih2, const float* __restrict__ bhh2,
    const float* __restrict__ pre1_t, int mode)
{
  __shared__ float sg[4][64][17];
  int bid = blockIdx.x, tid = threadIdx.x;
  int g = tid >> 6, lane = tid & 63;
  int la = lane & 15, q = lane >> 4;
  bool is2 = (mode == 1) && (bid < 64);
  int jb = is2 ? bid : (mode == 1 ? bid - 64 : bid);
  int j0 = jb * 16;
  bool active = is2 || (pre1_t != nullptr);

  if (active){
    f32x4 acc[4];
    #pragma unroll
    for (int mi = 0; mi < 4; mi++) acc[mi] = (f32x4){0.f, 0.f, 0.f, 0.f};
    int n0 = g * 1024 + j0;
    if (is2){
      // flat K = [h1(t) | o(t-1) | h2(t-1)]; wih2 cols [0,2048), whh2 cols [0,1024)
      gseg(32, h1cur,  0, wih2, 2048, 0,    la, q, n0, acc);
      gseg(32, oh,     0, wih2, 2048, 1024, la, q, n0, acc);
      gseg(32, h2prev, 0, whh2, 1024, 0,    la, q, n0, acc);
    } else {
      gseg(32, h1cur,  0, whh1, 1024, 0,    la, q, n0, acc);
    }
    #pragma unroll
    for (int mi = 0; mi < 4; mi++)
      #pragma unroll
      for (int r = 0; r < 4; r++)
        sg[g][mi * 16 + q * 4 + r][la] = acc[mi][r];
  }
  __syncthreads();
  if (active){
    for (int e = tid; e < 1024; e += 256){
      int row = e >> 4, col = e & 15, j = j0 + col;
      float gi = sg[0][row][col];
      float gf = sg[1][row][col];
      float gg = sg[2][row][col];
      float go = sg[3][row][col];
      if (is2){
        gi += bih2[j] + bhh2[j];
        gf += bih2[j + 1024] + bhh2[j + 1024];
        gg += bih2[j + 2048] + bhh2[j + 2048];
        go += bih2[j + 3072] + bhh2[j + 3072];
        float c_ = sigf(gf) * c2[row * Hn + j] + sigf(gi) * tanhf(gg);
        c2[row * Hn + j] = c_;
        float h_ = sigf(go) * tanhf(c_);
        h2cur[row * Hn + j] = (h16)h_;
        h2f[row * Hn + j] = h_;
      } else {
        const float* p = pre1_t + (size_t)row * Gn;   // includes bih1+bhh1
        gi += p[j]; gf += p[j + 1024]; gg += p[j + 2048]; go += p[j + 3072];
        float c_ = sigf(gf) * c1[row * Hn + j] + sigf(gi) * tanhf(gg);
        c1[row * Hn + j] = c_;
        h1next[row * Hn + j] = (h16)(sigf(go) * tanhf(c_));
      }
    }
  }
}

// ---------------- kB: e-dots (blocks 0-511) || hw = h2@Wcomb_b + bcomb (blocks 512-527) ----
__global__ __launch_bounds__(256, 4) void kB(
    const float* __restrict__ h2f, const h16* __restrict__ eph, const int* __restrict__ msk,
    float* __restrict__ ebuf,
    const h16* __restrict__ h2cur, const h16* __restrict__ wcomb, const float* __restrict__ bcomb,
    float* __restrict__ hwb)
{
  int bid = blockIdx.x, tid = threadIdx.x;
  int w = tid >> 6, lane = tid & 63;
  if (bid < 512){
    int wv = bid * 4 + w;           // 0..2047
    int b = wv >> 5;
    int l0 = (wv & 31) * 4;
    const float* h2r = h2f + b * Hn + lane * 16;
    float hv[16];
    #pragma unroll
    for (int i = 0; i < 16; i++) hv[i] = h2r[i];
    for (int li = 0; li < 4; li++){
      int l = l0 + li;
      const h16* er = eph + ((size_t)b * Ln + l) * Hn + lane * 16;
      float acc = 0.f;
      #pragma unroll
      for (int i = 0; i < 16; i++) acc += hv[i] * (float)er[i];
      for (int off = 32; off; off >>= 1) acc += __shfl_xor(acc, off);
      if (lane == 0) ebuf[b * Ln + l] = msk[b * Ln + l] ? -1e30f : acc;
    }
  } else {
    int hb = bid - 512;             // 0..15
    int la = lane & 15, q = lane >> 4;
    int n0 = hb * 64 + w * 16;
    f32x4 acc[4];
    #pragma unroll
    for (int mi = 0; mi < 4; mi++) acc[mi] = (f32x4){0.f, 0.f, 0.f, 0.f};
    for (int s = 0; s < 32; s++){
      int k = s * 32 + q * 8;
      h16x8 af[4], bf;
      #pragma unroll
      for (int mi = 0; mi < 4; mi++)
        af[mi] = *reinterpret_cast<const h16x8*>(h2cur + (size_t)(mi * 16 + la) * Hn + k);
      bf = *reinterpret_cast<const h16x8*>(wcomb + (size_t)(n0 + la) * (HEn + Hn) + HEn + k);
      #pragma unroll
      for (int mi = 0; mi < 4; mi++)
        acc[mi] = __builtin_amdgcn_mfma_f32_16x16x32_f16(af[mi], bf, acc[mi], 0, 0, 0);
    }
    float bs = bcomb[n0 + la];
    #pragma unroll
    for (int mi = 0; mi < 4; mi++)
      #pragma unroll
      for (int r = 0; r < 4; r++)
        hwb[(size_t)(mi * 16 + q * 4 + r) * Hn + n0 + la] = acc[mi][r] + bs;
  }
}

// ---------------- kC: softmax + o_t = tanh(sum_l alpha*enc_comb + hw) ----------------
__global__ __launch_bounds__(256, 4) void kC(
    int t, const float* __restrict__ ebuf,
    const h16* __restrict__ ecbh, const float* __restrict__ hwb,
    float* __restrict__ out, h16* __restrict__ oh)
{
  __shared__ float sa[Ln], sb[Ln];
  int bid = blockIdx.x;
  int b = bid >> 1;
  int jh = (bid & 1) * 512;
  int tid = threadIdx.x;
  if (tid < Ln) sa[tid] = ebuf[b * Ln + tid];
  __syncthreads();
  float m = -1e30f;
  for (int l = 0; l < Ln; l++) m = fmaxf(m, sa[l]);
  if (tid < Ln) sb[tid] = expf(sa[tid] - m);
  __syncthreads();
  float s = 0.f;
  for (int l = 0; l < Ln; l++) s += sb[l];
  float rinv = 1.f / s;
  int j0 = jh + tid * 2;
  const h16* base = ecbh + (size_t)b * Ln * Hn + j0;
  float a0 = 0.f, a1 = 0.f;
  for (int l = 0; l < Ln; l++){
    float al = sb[l];
    h16x2 pq = *reinterpret_cast<const h16x2*>(base + (size_t)l * Hn);
    a0 += al * (float)pq.x;
    a1 += al * (float)pq.y;
  }
  a0 *= rinv; a1 *= rinv;
  float2 hw2 = *reinterpret_cast<const float2*>(hwb + b * Hn + j0);   // bias included
  float o0 = tanhf(a0 + hw2.x);
  float o1 = tanhf(a1 + hw2.y);
  *reinterpret_cast<float2*>(out + ((size_t)t * Bn + b) * Hn + j0) = make_float2(o0, o1);
  h16x2 opk; opk.x = (h16)o0; opk.y = (h16)o1;
  *reinterpret_cast<h16x2*>(oh + b * Hn + j0) = opk;
}

// ---------------- host ----------------
extern "C" void kernel_launch(void* const* d_in, const int* in_sizes, int n_in,
                              void* d_out, int out_size, void* d_ws, size_t ws_size,
                              hipStream_t stream)
{
  const float* enc   = (const float*)d_in[0];
  const int*   msk   = (const int*)  d_in[1];
  const float* h1i   = (const float*)d_in[2];
  const float* c1i   = (const float*)d_in[3];
  const float* h2i   = (const float*)d_in[4];
  const float* c2i   = (const float*)d_in[5];
  const float* caps  = (const float*)d_in[6];
  const float* Wih1  = (const float*)d_in[7];
  const float* Whh1  = (const float*)d_in[8];
  const float* bih1  = (const float*)d_in[9];
  const float* bhh1  = (const float*)d_in[10];
  const float* Wih2  = (const float*)d_in[11];
  const float* Whh2  = (const float*)d_in[12];
  const float* bih2  = (const float*)d_in[13];
  const float* bhh2  = (const float*)d_in[14];
  const float* Watt  = (const float*)d_in[15];
  const float* batt  = (const float*)d_in[16];
  const float* Wcomb = (const float*)d_in[17];
  const float* bcomb = (const float*)d_in[18];
  float* out = (float*)d_out;

  char* p = (char*)d_ws;
  auto take = [&](size_t bytes){ char* r = p; p += (bytes + 255) & ~(size_t)255; return r; };
  float* pre1   = (float*)take((size_t)Tn * Bn * Gn * 4);          // 50.3 MB
  h16*   ench   = (h16*)take((size_t)Bn * Ln * HEn * 2);
  h16*   eph    = (h16*)take((size_t)Bn * Ln * Hn * 2);
  h16*   ecbh   = (h16*)take((size_t)Bn * Ln * Hn * 2);
  h16*   caph   = (h16*)take((size_t)Tn * Bn * En * 2);
  h16*   wih1h  = (h16*)take((size_t)Gn * En * 2);
  h16*   whh1h  = (h16*)take((size_t)Gn * Hn * 2);
  h16*   wih2h  = (h16*)take((size_t)Gn * 2 * Hn * 2);
  h16*   whh2h  = (h16*)take((size_t)Gn * Hn * 2);
  h16*   watth  = (h16*)take((size_t)Hn * HEn * 2);
  h16*   wcombh = (h16*)take((size_t)Hn * (HEn + Hn) * 2);
  h16*   h1b0   = (h16*)take((size_t)Bn * Hn * 2);
  h16*   h1b1   = (h16*)take((size_t)Bn * Hn * 2);
  h16*   h2b0   = (h16*)take((size_t)Bn * Hn * 2);
  h16*   h2b1   = (h16*)take((size_t)Bn * Hn * 2);
  h16*   oh     = (h16*)take((size_t)Bn * Hn * 2);
  float* c1     = (float*)take((size_t)Bn * Hn * 4);
  float* c2     = (float*)take((size_t)Bn * Hn * 4);
  float* h2f    = (float*)take((size_t)Bn * Hn * 4);
  float* ebuf   = (float*)take((size_t)Bn * Ln * 4);
  float* hwb    = (float*)take((size_t)Bn * Hn * 4);
  (void)ws_size; (void)n_in; (void)in_sizes; (void)out_size;

  auto cvt = [&](const float* src, void* dst, int n){
    int n2 = n / 2;
    int blocks = (n2 + 255) / 256; if (blocks > 2048) blocks = 2048;
    cvt2<<<blocks, 256, 0, stream>>>(src, (h16x2*)dst, n2);
  };
  cvt(enc,   ench,   Bn * Ln * HEn);
  cvt(caps,  caph,   Tn * Bn * En);
  cvt(Wih1,  wih1h,  Gn * En);
  cvt(Whh1,  whh1h,  Gn * Hn);
  cvt(Wih2,  wih2h,  Gn * 2 * Hn);
  cvt(Whh2,  whh2h,  Gn * Hn);
  cvt(Watt,  watth,  Hn * HEn);
  cvt(Wcomb, wcombh, Hn * (HEn + Hn));

  init_state<<<(Bn * Hn) / 256, 256, 0, stream>>>(h1i, c1i, h2i, c2i,
                                                  h1b0, c1, h2b0, c2, h2f, oh);

  // pre1 = captions @ Wih1^T + bih1 + bhh1   (3072 x 4096, K=512)
  gemm8<<<dim3((Tn * Bn) / 64, Gn / 128), 256, 0, stream>>>(
      caph, En, wih1h, En, bih1, bhh1, pre1, nullptr, Gn, En);
  // enc_proj = enc @ Watt^T + batt  (8192 x 1024, K=1024) -> fp16
  gemm8<<<dim3((Bn * Ln) / 64, Hn / 128), 256, 0, stream>>>(
      ench, HEn, watth, HEn, batt, nullptr, nullptr, eph, Hn, HEn);
  // enc_comb = enc @ Wcomb[:, :HE]^T  (8192 x 1024, K=1024) -> fp16
  gemm8<<<dim3((Bn * Ln) / 64, Hn / 128), 256, 0, stream>>>(
      ench, HEn, wcombh, HEn + Hn, nullptr, nullptr, nullptr, ecbh, Hn, HEn);

  // prime: gates1(0) -> h1(0) in h1b1 (h1 state for t lives in h1buf[(t+1)&1])
  kA<<<64, 256, 0, stream>>>(h1b0, h2b0, oh, h1b1, h2b1, h2f, c1, c2,
                             wih2h, whh2h, whh1h, bih2, bhh2, pre1, /*mode=*/0);

  h16* h1buf[2] = { h1b0, h1b1 };
  h16* h2buf[2] = { h2b0, h2b1 };
  for (int t = 0; t < Tn; t++){
    h16* h1cur  = h1buf[(t + 1) & 1];
    h16* h1next = h1buf[t & 1];
    h16* h2prev = h2buf[t & 1];
    h16* h2cur  = h2buf[(t + 1) & 1];
    const float* pre1_t = (t + 1 < Tn) ? (pre1 + (size_t)(t + 1) * Bn * Gn) : nullptr;
    kA<<<128, 256, 0, stream>>>(h1cur, h2prev, oh, h1next, h2cur, h2f, c1, c2,
                                wih2h, whh2h, whh1h, bih2, bhh2, pre1_t, /*mode=*/1);
    kB<<<528, 256, 0, stream>>>(h2f, eph, msk, ebuf, h2cur, wcombh, bcomb, hwb);
    kC<<<128, 256, 0, stream>>>(t, ebuf, ecbh, hwb, out, oh);
  }
}